// Round 1
// baseline (200.885 us; speedup 1.0000x reference)
//
#include <hip/hip_runtime.h>
#include <math.h>

// pHMM forward (log2 space) + KLD, one wave (64 lanes) per batch element.
// Lane j holds state j+1; state 0 is wave-uniform. Delete-chain handled by a
// 6-step log-semiring shuffle scan with precomputed (l-independent) d-segment
// sums U1..U6.

namespace {

constexpr float kLog2e = 1.4426950408889634f;
constexpr float kLn2   = 0.6931471805599453f;
constexpr float kNeg2  = -100.0f * kLog2e;  // NEG in log2 units
constexpr float kLogQ2 = -2.0f;             // log2(0.25)

__device__ __forceinline__ float lae2(float x, float y) {
    float m = fmaxf(x, y);
    float t = __builtin_amdgcn_exp2f(-fabsf(x - y));
    return m + __builtin_amdgcn_logf(1.0f + t);   // v_log_f32 = log2
}

__device__ __forceinline__ float lae2_3(float x, float y, float z) {
    float m = fmaxf(fmaxf(x, y), z);
    float t = __builtin_amdgcn_exp2f(x - m) + __builtin_amdgcn_exp2f(y - m) +
              __builtin_amdgcn_exp2f(z - m);
    return m + __builtin_amdgcn_logf(t);
}

__global__ __launch_bounds__(256) void phmm_vae_kernel(
    const int* __restrict__ xg,    // (B,128) int32
    const float* __restrict__ ag,  // (B,65,7)
    const float* __restrict__ eg,  // (B,64,4)
    const float* __restrict__ mug, // (B,16)
    const float* __restrict__ lvg, // (B,16)
    float* __restrict__ out, int B)
{
    const int tid  = threadIdx.x;
    const int lane = tid & 63;
    const int wv   = tid >> 6;
    const int b    = (blockIdx.x << 2) + wv;

    __shared__ float part[4];
    float contrib = 0.0f;

    if (b < B) {
        const float* ab = ag + (size_t)b * (65 * 7);
        const float* eb = eg + (size_t)b * (64 * 4);
        const int*   xb = xg + (size_t)b * 128;

        const int j = lane;
        // d-chain coefficients for position j+1 use row j.
        float ajM2D = ab[j * 7 + 2] * kLog2e;
        float ajD2D = ab[j * 7 + 6] * kLog2e;
        // own-state (j+1) coefficients.  Lane 63 row = 64 = final state.
        float a1M2M = ab[(j + 1) * 7 + 0] * kLog2e;
        float a1M2I = ab[(j + 1) * 7 + 1] * kLog2e;
        float a1I2M = ab[(j + 1) * 7 + 3] * kLog2e;
        float a1I2I = ab[(j + 1) * 7 + 4] * kLog2e;
        float a1D2M = ab[(j + 1) * 7 + 5] * kLog2e;
        // state-0 row (wave-uniform).
        float a0M2M = ab[0] * kLog2e;
        float a0M2I = ab[1] * kLog2e;
        float a0I2M = ab[3] * kLog2e;
        float a0I2I = ab[4] * kLog2e;
        float a0D2M = ab[5] * kLog2e;

        float4 ev = *reinterpret_cast<const float4*>(eb + j * 4);
        float e0 = ev.x * kLog2e, e1 = ev.y * kLog2e;
        float e2 = ev.z * kLog2e, e3 = ev.w * kLog2e;

        int xlo = xb[lane];
        int xhi = xb[64 + lane];

        // Precompute d-scan segment sums (l-independent).
        float U1 = ajD2D, t;
        t = __shfl_up(U1, 1, 64);  float U2 = (lane >= 1)  ? U1 + t : U1;
        t = __shfl_up(U2, 2, 64);  float U3 = (lane >= 2)  ? U2 + t : U2;
        t = __shfl_up(U3, 4, 64);  float U4 = (lane >= 4)  ? U3 + t : U3;
        t = __shfl_up(U4, 8, 64);  float U5 = (lane >= 8)  ? U4 + t : U4;
        t = __shfl_up(U5, 16, 64); float U6 = (lane >= 16) ? U5 + t : U5;
        t = __shfl_up(U6, 32, 64); float DF = (lane >= 32) ? U6 + t : U6;
        const float DN = DF + kNeg2;  // full prefix + y_init

        auto dchain = [&](float fMn, float fM0n) -> float {
            float fMp = __shfl_up(fMn, 1, 64);
            if (lane == 0) fMp = fM0n;
            float c = ajM2D + fMp;
            float cp, cn;
            cp = __shfl_up(c, 1, 64);  cn = lae2(c, U1 + cp); c = (lane >= 1)  ? cn : c;
            cp = __shfl_up(c, 2, 64);  cn = lae2(c, U2 + cp); c = (lane >= 2)  ? cn : c;
            cp = __shfl_up(c, 4, 64);  cn = lae2(c, U3 + cp); c = (lane >= 4)  ? cn : c;
            cp = __shfl_up(c, 8, 64);  cn = lae2(c, U4 + cp); c = (lane >= 8)  ? cn : c;
            cp = __shfl_up(c, 16, 64); cn = lae2(c, U5 + cp); c = (lane >= 16) ? cn : c;
            cp = __shfl_up(c, 32, 64); cn = lae2(c, U6 + cp); c = (lane >= 32) ? cn : c;
            return lae2(c, DN);
        };

        // Forward state in log2 units.
        float fM = kNeg2, fI = kNeg2;
        float fM0 = 0.0f, fI0 = kNeg2;
        float fD = dchain(fM, fM0);

        for (int l = 0; l < 128; ++l) {
            int xl = __shfl((l < 64) ? xlo : xhi, l & 63, 64);
            float esel = (xl & 2) ? ((xl & 1) ? e3 : e2)
                                  : ((xl & 1) ? e1 : e0);

            float pl = lae2_3(a1M2M + fM, a1I2M + fI, a1D2M + fD);
            float p0 = lae2_3(a0M2M + fM0, a0I2M + fI0, a0D2M + kNeg2);
            float prev = __shfl_up(pl, 1, 64);
            if (lane == 0) prev = p0;
            float fMn = esel + prev;

            fI  = kLogQ2 + lae2(a1M2I + fM,  a1I2I + fI);
            fI0 = kLogQ2 + lae2(a0M2I + fM0, a0I2I + fI0);

            fD = dchain(fMn, kNeg2);
            fM = fMn;
            fM0 = kNeg2;
        }

        // Final logsumexp at state K=64 lives in lane 63 (its row = 64).
        float res  = lae2_3(fM + a1M2M, fI + a1I2M, fD + a1D2M);
        float loss = -res * kLn2;

        // KLD on lanes 0..15.
        float kt = 0.0f;
        if (lane < 16) {
            float mu = mug[(size_t)b * 16 + lane];
            float lv = lvg[(size_t)b * 16 + lane];
            kt = 1.0f + lv - mu * mu - __builtin_amdgcn_exp2f(lv * kLog2e);
        }
        kt += __shfl_xor(kt, 1, 64);
        kt += __shfl_xor(kt, 2, 64);
        kt += __shfl_xor(kt, 4, 64);
        kt += __shfl_xor(kt, 8, 64);
        float kldb = __shfl(-0.5f * kt, 0, 64);

        contrib = (loss + kldb) * (1.0f / 4096.0f);
    }

    if (lane == 63) part[wv] = (b < B) ? contrib : 0.0f;
    __syncthreads();
    if (tid == 0) {
        atomicAdd(out, part[0] + part[1] + part[2] + part[3]);
    }
}

__global__ void zero_out_kernel(float* out) { out[0] = 0.0f; }

}  // namespace

extern "C" void kernel_launch(void* const* d_in, const int* in_sizes, int n_in,
                              void* d_out, int out_size, void* d_ws, size_t ws_size,
                              hipStream_t stream) {
    const int*   x  = (const int*)d_in[0];
    const float* a  = (const float*)d_in[1];
    const float* e  = (const float*)d_in[2];
    const float* mu = (const float*)d_in[3];
    const float* lv = (const float*)d_in[4];
    float* out = (float*)d_out;

    const int B = in_sizes[0] / 128;      // 4096
    const int grid = (B + 3) / 4;         // 4 waves (batch elements) per block

    zero_out_kernel<<<1, 1, 0, stream>>>(out);
    phmm_vae_kernel<<<grid, 256, 0, stream>>>(x, a, e, mu, lv, out, B);
}

// Round 2
// 156.238 us; speedup vs baseline: 1.2858x; 1.2858x over previous
//
#include <hip/hip_runtime.h>
#include <math.h>

// pHMM forward (log2 space) + KLD, one wave (64 lanes) per batch element.
// Lane j holds state j+1; state 0 handled by closed form (NEG ~ -inf).
// Delete-chain = 6-step log-semiring shuffle scan with premasked,
// l-independent d-segment sums U1m..U6m. x symbols carried as SGPR ballot
// masks (scalar-pipe extraction, no LDS broadcast per step).

namespace {

constexpr float kLog2e = 1.4426950408889634f;
constexpr float kLn2   = 0.6931471805599453f;
constexpr float kNeg2  = -100.0f * kLog2e;  // NEG in log2 units
constexpr float kLogQ2 = -2.0f;             // log2(0.25)
constexpr float kMask  = -3.0e4f;           // "minus infinity" for masked scan lanes

__device__ __forceinline__ float lae2(float x, float y) {
    float m = fmaxf(x, y);
    float t = __builtin_amdgcn_exp2f(-fabsf(x - y));
    return m + __builtin_amdgcn_logf(1.0f + t);   // v_log_f32 = log2
}

__device__ __forceinline__ float lae2_3(float x, float y, float z) {
    float m = fmaxf(fmaxf(x, y), z);               // v_max3
    float t = __builtin_amdgcn_exp2f(x - m) + __builtin_amdgcn_exp2f(y - m) +
              __builtin_amdgcn_exp2f(z - m);
    return m + __builtin_amdgcn_logf(t);
}

__global__ __launch_bounds__(256) void phmm_vae_kernel(
    const int* __restrict__ xg,    // (B,128) int32
    const float* __restrict__ ag,  // (B,65,7)
    const float* __restrict__ eg,  // (B,64,4)
    const float* __restrict__ mug, // (B,16)
    const float* __restrict__ lvg, // (B,16)
    float* __restrict__ out, int B)
{
    const int tid  = threadIdx.x;
    const int lane = tid & 63;
    const int wv   = tid >> 6;
    const int b    = (blockIdx.x << 2) + wv;

    __shared__ float part[4];
    float contrib = 0.0f;

    if (b < B) {
        const float* ab = ag + (size_t)b * (65 * 7);
        const float* eb = eg + (size_t)b * (64 * 4);
        const int*   xb = xg + (size_t)b * 128;

        const int j = lane;
        // d-chain coefficients for position j+1 use row j.
        const float ajM2D = ab[j * 7 + 2] * kLog2e;
        const float ajD2D = ab[j * 7 + 6] * kLog2e;
        // own-state (j+1) coefficients.  Lane 63 row = 64 = final state.
        const float a1M2M  = ab[(j + 1) * 7 + 0] * kLog2e;
        const float a1M2Iq = ab[(j + 1) * 7 + 1] * kLog2e + kLogQ2;
        const float a1I2M  = ab[(j + 1) * 7 + 3] * kLog2e;
        const float a1I2Iq = ab[(j + 1) * 7 + 4] * kLog2e + kLogQ2;
        const float a1D2M  = ab[(j + 1) * 7 + 5] * kLog2e;
        // state-0 row (wave-uniform).
        const float a0M2M = ab[0] * kLog2e;
        const float a0M2I = ab[1] * kLog2e;
        const float a0I2M = ab[3] * kLog2e;
        const float a0I2I = ab[4] * kLog2e;
        const float a0D2M = ab[5] * kLog2e;

        float4 ev = *reinterpret_cast<const float4*>(eb + j * 4);
        const float e0 = ev.x * kLog2e, e1 = ev.y * kLog2e;
        const float e2 = ev.z * kLog2e, e3 = ev.w * kLog2e;

        const int xlo = xb[lane];
        const int xhi = xb[64 + lane];
        // Pack symbols into wave-uniform 64-bit ballot masks (SGPRs).
        const unsigned long long b0lo = __ballot(xlo & 1);
        const unsigned long long b1lo = __ballot(xlo & 2);
        const unsigned long long b0hi = __ballot(xhi & 1);
        const unsigned long long b1hi = __ballot(xhi & 2);

        // Precompute d-scan segment sums (l-independent), then premask.
        float U1 = ajD2D, t;
        t = __shfl_up(U1, 1, 64);  float U2 = (lane >= 1)  ? U1 + t : U1;
        t = __shfl_up(U2, 2, 64);  float U3 = (lane >= 2)  ? U2 + t : U2;
        t = __shfl_up(U3, 4, 64);  float U4 = (lane >= 4)  ? U3 + t : U3;
        t = __shfl_up(U4, 8, 64);  float U5 = (lane >= 8)  ? U4 + t : U4;
        t = __shfl_up(U5, 16, 64); float U6 = (lane >= 16) ? U5 + t : U5;
        const float U1m = (lane >= 1)  ? U1 : kMask;
        const float U2m = (lane >= 2)  ? U2 : kMask;
        const float U3m = (lane >= 4)  ? U3 : kMask;
        const float U4m = (lane >= 8)  ? U4 : kMask;
        const float U5m = (lane >= 16) ? U5 : kMask;
        const float U6m = (lane >= 32) ? U6 : kMask;

        auto dchain = [&](float fMn, float f0) -> float {
            float fMp = __shfl_up(fMn, 1, 64);
            float c = ajM2D + ((lane == 0) ? f0 : fMp);
            float cp;
            cp = __shfl_up(c, 1, 64);  c = lae2(c, U1m + cp);
            cp = __shfl_up(c, 2, 64);  c = lae2(c, U2m + cp);
            cp = __shfl_up(c, 4, 64);  c = lae2(c, U3m + cp);
            cp = __shfl_up(c, 8, 64);  c = lae2(c, U4m + cp);
            cp = __shfl_up(c, 16, 64); c = lae2(c, U5m + cp);
            cp = __shfl_up(c, 32, 64); c = lae2(c, U6m + cp);
            return c;
        };

        // Forward state in log2 units.
        float fM = kNeg2, fI = kNeg2;
        float fD = dchain(fM, 0.0f);   // init: fM0 = 0

        auto stepf = [&](float esel, float p0) {
            float pl = lae2_3(a1M2M + fM, a1I2M + fI, a1D2M + fD);
            float prev = __shfl_up(pl, 1, 64);
            prev = (lane == 0) ? p0 : prev;
            float fMn = esel + prev;
            fI = lae2(a1M2Iq + fM, a1I2Iq + fI);
            fD = dchain(fMn, kNeg2);
            fM = fMn;
        };

        auto esel_of = [&](unsigned long long m0, unsigned long long m1,
                           int sh) -> float {
            int bit0 = (int)(m0 >> sh) & 1;
            int bit1 = (int)(m1 >> sh) & 1;
            float eA = bit0 ? e1 : e0;
            float eB = bit0 ? e3 : e2;
            return bit1 ? eB : eA;
        };

        // l = 0 peeled: state-0 values exact.
        {
            float p00 = lae2_3(a0M2M, a0I2M + kNeg2, a0D2M + kNeg2);
            stepf(esel_of(b0lo, b1lo, 0), p00);
        }
        // Closed-form state-0 recurrence thereafter (NEG treated as -inf;
        // dropped terms are at the 2^-144 level -> exact in fp32).
        float fI0v = kLogQ2 + lae2(a0M2I, a0I2I + kNeg2);  // fI0 after step 0
        const float d0 = kLogQ2 + a0I2I;

        for (int l = 1; l < 64; ++l) {
            stepf(esel_of(b0lo, b1lo, l), a0I2M + fI0v);
            fI0v += d0;
        }
        for (int l = 0; l < 64; ++l) {
            stepf(esel_of(b0hi, b1hi, l), a0I2M + fI0v);
            fI0v += d0;
        }

        // Final logsumexp at state K=64 lives in lane 63 (its row = 64).
        float res  = lae2_3(fM + a1M2M, fI + a1I2M, fD + a1D2M);
        float loss = -res * kLn2;

        // KLD on lanes 0..15.
        float kt = 0.0f;
        if (lane < 16) {
            float mu = mug[(size_t)b * 16 + lane];
            float lv = lvg[(size_t)b * 16 + lane];
            kt = 1.0f + lv - mu * mu - __builtin_amdgcn_exp2f(lv * kLog2e);
        }
        kt += __shfl_xor(kt, 1, 64);
        kt += __shfl_xor(kt, 2, 64);
        kt += __shfl_xor(kt, 4, 64);
        kt += __shfl_xor(kt, 8, 64);
        float kldb = __shfl(-0.5f * kt, 0, 64);

        contrib = (loss + kldb) * (1.0f / 4096.0f);
    }

    if (lane == 63) part[wv] = (b < B) ? contrib : 0.0f;
    __syncthreads();
    if (tid == 0) {
        atomicAdd(out, part[0] + part[1] + part[2] + part[3]);
    }
}

__global__ void zero_out_kernel(float* out) { out[0] = 0.0f; }

}  // namespace

extern "C" void kernel_launch(void* const* d_in, const int* in_sizes, int n_in,
                              void* d_out, int out_size, void* d_ws, size_t ws_size,
                              hipStream_t stream) {
    const int*   x  = (const int*)d_in[0];
    const float* a  = (const float*)d_in[1];
    const float* e  = (const float*)d_in[2];
    const float* mu = (const float*)d_in[3];
    const float* lv = (const float*)d_in[4];
    float* out = (float*)d_out;

    const int B = in_sizes[0] / 128;      // 4096
    const int grid = (B + 3) / 4;         // 4 waves (batch elements) per block

    zero_out_kernel<<<1, 1, 0, stream>>>(out);
    phmm_vae_kernel<<<grid, 256, 0, stream>>>(x, a, e, mu, lv, out, B);
}

// Round 3
// 130.692 us; speedup vs baseline: 1.5371x; 1.1955x over previous
//
#include <hip/hip_runtime.h>
#include <math.h>

// pHMM forward in LINEAR space (scaled) + KLD. One wave per batch element,
// lane j = state j+1; state 0 via closed form. Every logaddexp replaced by
// add/FMA; delete-chain = 6-level FMA shuffle scan with l-independent,
// premasked segment products V1m..V6m. Rescale every 8 steps (wave max3 +
// rcp), scale accumulated in log2. Transcendentals only at setup/epilogue.

namespace {

constexpr float kLog2e = 1.4426950408889634f;
constexpr float kLn2   = 0.6931471805599453f;

__device__ __forceinline__ float fexp(float x) {  // e^x
    return __builtin_amdgcn_exp2f(x * kLog2e);
}

__global__ __launch_bounds__(256) void phmm_vae_kernel(
    const int* __restrict__ xg,    // (B,128) int32
    const float* __restrict__ ag,  // (B,65,7)
    const float* __restrict__ eg,  // (B,64,4)
    const float* __restrict__ mug, // (B,16)
    const float* __restrict__ lvg, // (B,16)
    float* __restrict__ out, int B)
{
    const int tid  = threadIdx.x;
    const int lane = tid & 63;
    const int wv   = tid >> 6;
    const int b    = (blockIdx.x << 2) + wv;

    __shared__ float part[4];
    float contrib = 0.0f;

    if (b < B) {
        const float* ab = ag + (size_t)b * (65 * 7);
        const float* eb = eg + (size_t)b * (64 * 4);
        const int*   xb = xg + (size_t)b * 128;

        const int j = lane;
        // Linear-space coefficients. Row j: d-chain for state j+1.
        const float AjM2D  = fexp(ab[j * 7 + 2]);
        const float AjD2D  = fexp(ab[j * 7 + 6]);
        // Row j+1: own-state coefficients (lane 63 row = 64 = final state).
        const float A1M2M  = fexp(ab[(j + 1) * 7 + 0]);
        const float QA1M2I = 0.25f * fexp(ab[(j + 1) * 7 + 1]);
        const float A1I2M  = fexp(ab[(j + 1) * 7 + 3]);
        const float QA1I2I = 0.25f * fexp(ab[(j + 1) * 7 + 4]);
        const float A1D2M  = fexp(ab[(j + 1) * 7 + 5]);
        // State-0 row (wave-uniform).
        const float A0M2M  = fexp(ab[0]);
        const float QA0M2I = 0.25f * fexp(ab[1]);
        const float A0I2M  = fexp(ab[3]);
        const float D0     = 0.25f * fexp(ab[4]);

        float4 ev = *reinterpret_cast<const float4*>(eb + j * 4);
        const float E0 = fexp(ev.x), E1 = fexp(ev.y);
        const float E2 = fexp(ev.z), E3 = fexp(ev.w);

        const int xlo = xb[lane];
        const int xhi = xb[64 + lane];
        const unsigned long long b0lo = __ballot(xlo & 1);
        const unsigned long long b1lo = __ballot(xlo & 2);
        const unsigned long long b0hi = __ballot(xhi & 1);
        const unsigned long long b1hi = __ballot(xhi & 2);

        // Segment products of D2D (l-independent), premasked to 0.
        float V1 = AjD2D, t;
        t = __shfl_up(V1, 1, 64);  float V2 = (lane >= 1)  ? V1 * t : V1;
        t = __shfl_up(V2, 2, 64);  float V3 = (lane >= 2)  ? V2 * t : V2;
        t = __shfl_up(V3, 4, 64);  float V4 = (lane >= 4)  ? V3 * t : V3;
        t = __shfl_up(V4, 8, 64);  float V5 = (lane >= 8)  ? V4 * t : V4;
        t = __shfl_up(V5, 16, 64); float V6 = (lane >= 16) ? V5 * t : V5;
        const float V1m = (lane >= 1)  ? V1 : 0.0f;
        const float V2m = (lane >= 2)  ? V2 : 0.0f;
        const float V3m = (lane >= 4)  ? V3 : 0.0f;
        const float V4m = (lane >= 8)  ? V4 : 0.0f;
        const float V5m = (lane >= 16) ? V5 : 0.0f;
        const float V6m = (lane >= 32) ? V6 : 0.0f;

        auto dchain = [&](float fMn, float f0) -> float {
            float fMp = __shfl_up(fMn, 1, 64);
            fMp = (lane == 0) ? f0 : fMp;
            float y = AjM2D * fMp;
            float yp;
            yp = __shfl_up(y, 1, 64);  y = fmaf(V1m, yp, y);
            yp = __shfl_up(y, 2, 64);  y = fmaf(V2m, yp, y);
            yp = __shfl_up(y, 4, 64);  y = fmaf(V3m, yp, y);
            yp = __shfl_up(y, 8, 64);  y = fmaf(V4m, yp, y);
            yp = __shfl_up(y, 16, 64); y = fmaf(V5m, yp, y);
            yp = __shfl_up(y, 32, 64); y = fmaf(V6m, yp, y);
            return y;
        };

        auto esel_of = [&](unsigned long long m0, unsigned long long m1,
                           int sh) -> float {
            int bit0 = (int)(m0 >> sh) & 1;
            int bit1 = (int)(m1 >> sh) & 1;
            float eA = bit0 ? E1 : E0;
            float eB = bit0 ? E3 : E2;
            return bit1 ? eB : eA;
        };

        // State (scaled linear space).
        float fM = 0.0f, fI = 0.0f;
        float fD = dchain(0.0f, 1.0f);   // init: fM0 = 1
        float LS = 0.0f;                 // accumulated log2 scale

        auto stepf = [&](float esel, float p0) {
            float pl = fmaf(A1M2M, fM, fmaf(A1I2M, fI, A1D2M * fD));
            float prev = __shfl_up(pl, 1, 64);
            prev = (lane == 0) ? p0 : prev;
            float fMn = esel * prev;
            fI = fmaf(QA1M2I, fM, QA1I2I * fI);
            fD = dchain(fMn, 0.0f);
            fM = fMn;
        };

        // l = 0 peeled: only state-0 M path live.
        stepf(esel_of(b0lo, b1lo, 0), A0M2M);
        float fI0v = QA0M2I;   // state-0 insert mass for step 1

        for (int l = 1; l < 128; ++l) {
            unsigned long long m0 = (l < 64) ? b0lo : b0hi;
            unsigned long long m1 = (l < 64) ? b1lo : b1hi;
            stepf(esel_of(m0, m1, l & 63), A0I2M * fI0v);
            fI0v *= D0;
            if ((l & 7) == 7) {
                float m = fmaxf(fmaxf(fM, fI), fD);
                m = fmaxf(m, __shfl_xor(m, 1, 64));
                m = fmaxf(m, __shfl_xor(m, 2, 64));
                m = fmaxf(m, __shfl_xor(m, 4, 64));
                m = fmaxf(m, __shfl_xor(m, 8, 64));
                m = fmaxf(m, __shfl_xor(m, 16, 64));
                m = fmaxf(m, __shfl_xor(m, 32, 64));
                m = fmaxf(m, 1e-35f);
                float r = __builtin_amdgcn_rcpf(m);
                LS += __builtin_amdgcn_logf(m);   // log2
                fM *= r; fI *= r; fD *= r; fI0v *= r;
            }
        }

        // Final logsumexp at state K=64 (lane 63, row 64 coefficients).
        float F = fmaf(A1M2M, fM, fmaf(A1I2M, fI, A1D2M * fD));
        float loss = -(__builtin_amdgcn_logf(F) + LS) * kLn2;

        // KLD on lanes 0..15.
        float kt = 0.0f;
        if (lane < 16) {
            float mu = mug[(size_t)b * 16 + lane];
            float lv = lvg[(size_t)b * 16 + lane];
            kt = 1.0f + lv - mu * mu - fexp(lv);
        }
        kt += __shfl_xor(kt, 1, 64);
        kt += __shfl_xor(kt, 2, 64);
        kt += __shfl_xor(kt, 4, 64);
        kt += __shfl_xor(kt, 8, 64);
        float kldb = __shfl(-0.5f * kt, 0, 64);

        contrib = (loss + kldb) * (1.0f / 4096.0f);
    }

    if (lane == 63) part[wv] = (b < B) ? contrib : 0.0f;
    __syncthreads();
    if (tid == 0) {
        atomicAdd(out, part[0] + part[1] + part[2] + part[3]);
    }
}

__global__ void zero_out_kernel(float* out) { out[0] = 0.0f; }

}  // namespace

extern "C" void kernel_launch(void* const* d_in, const int* in_sizes, int n_in,
                              void* d_out, int out_size, void* d_ws, size_t ws_size,
                              hipStream_t stream) {
    const int*   x  = (const int*)d_in[0];
    const float* a  = (const float*)d_in[1];
    const float* e  = (const float*)d_in[2];
    const float* mu = (const float*)d_in[3];
    const float* lv = (const float*)d_in[4];
    float* out = (float*)d_out;

    const int B = in_sizes[0] / 128;      // 4096
    const int grid = (B + 3) / 4;         // 4 waves (batch elements) per block

    zero_out_kernel<<<1, 1, 0, stream>>>(out);
    phmm_vae_kernel<<<grid, 256, 0, stream>>>(x, a, e, mu, lv, out, B);
}

// Round 4
// 110.061 us; speedup vs baseline: 1.8252x; 1.1875x over previous
//
#include <hip/hip_runtime.h>
#include <math.h>

// pHMM forward in LINEAR space (scaled) + KLD. One wave per batch element,
// lane j = state j+1; state 0 via closed form. Delete-chain = row-local DPP
// scan (row_shr 1/2/4/8) + cross-row propagation via row_bcast15/31 with
// precomputed D-prefix-product coefficients. ZERO LDS ops in the hot loop.
// Rescale every 8 steps by an exact power of 2 (exponent-field arithmetic,
// row-max via DPP mirrors + readlane/s_max). Single kernel: last block
// publishes the result (poison-based atomic counter in d_ws).

namespace {

constexpr float kLog2e = 1.4426950408889634f;
constexpr float kLn2   = 0.6931471805599453f;

__device__ __forceinline__ float fexp(float x) {  // e^x
    return __builtin_amdgcn_exp2f(x * kLog2e);
}

// DPP helper: CTRL = dpp_ctrl, BC = bound_ctrl (true -> invalid source reads 0;
// false -> invalid/masked lanes keep `old`).
template <int CTRL, bool BC>
__device__ __forceinline__ float dppf(float old, float src) {
    int r = __builtin_amdgcn_update_dpp(__builtin_bit_cast(int, old),
                                        __builtin_bit_cast(int, src),
                                        CTRL, 0xF, 0xF, BC);
    return __builtin_bit_cast(float, r);
}

__global__ __launch_bounds__(256) void phmm_vae_kernel(
    const int* __restrict__ xg,    // (B,128) int32
    const float* __restrict__ ag,  // (B,65,7)
    const float* __restrict__ eg,  // (B,64,4)
    const float* __restrict__ mug, // (B,16)
    const float* __restrict__ lvg, // (B,16)
    float* __restrict__ out, unsigned* __restrict__ wsc, float* __restrict__ wsf,
    int B)
{
    const int tid  = threadIdx.x;
    const int lane = tid & 63;
    const int wv   = tid >> 6;
    const int b    = (blockIdx.x << 2) + wv;

    __shared__ float part[4];
    float contrib = 0.0f;

    if (b < B) {
        const float* ab = ag + (size_t)b * (65 * 7);
        const float* eb = eg + (size_t)b * (64 * 4);
        const int*   xb = xg + (size_t)b * 128;

        const int j = lane;
        // Linear-space coefficients. Row j: d-chain for state j+1.
        const float AjM2D  = fexp(ab[j * 7 + 2]);
        const float d      = fexp(ab[j * 7 + 6]);   // AjD2D
        // Row j+1: own-state coefficients (lane 63 row = 64 = final state).
        const float A1M2M  = fexp(ab[(j + 1) * 7 + 0]);
        const float QA1M2I = 0.25f * fexp(ab[(j + 1) * 7 + 1]);
        const float A1I2M  = fexp(ab[(j + 1) * 7 + 3]);
        const float QA1I2I = 0.25f * fexp(ab[(j + 1) * 7 + 4]);
        const float A1D2M  = fexp(ab[(j + 1) * 7 + 5]);
        // State-0 row (wave-uniform).
        const float A0M2M  = fexp(ab[0]);
        const float QA0M2I = 0.25f * fexp(ab[1]);
        const float A0I2M  = fexp(ab[3]);
        const float D0     = 0.25f * fexp(ab[4]);

        float4 ev = *reinterpret_cast<const float4*>(eb + j * 4);
        const float E0 = fexp(ev.x), E1 = fexp(ev.y);
        const float E2 = fexp(ev.z), E3 = fexp(ev.w);

        const int xlo = xb[lane];
        const int xhi = xb[64 + lane];
        const unsigned long long b0lo = __ballot(xlo & 1);
        const unsigned long long b1lo = __ballot(xlo & 2);
        const unsigned long long b0hi = __ballot(xhi & 1);
        const unsigned long long b1hi = __ballot(xhi & 2);

        // Row-local segment products of d at distances 1/2/4/8 (only read by
        // lanes whose source is in-row; row_shr covers exactly those).
        const float V1 = d;
        const float V2 = V1 * dppf<0x111, false>(1.0f, V1);
        const float V4 = V2 * dppf<0x112, false>(1.0f, V2);
        const float V8 = V4 * dppf<0x114, false>(1.0f, V4);
        // Row-local inclusive prefix product Q[j] = prod_{rowstart..j} d.
        float Q = d;
        Q *= dppf<0x111, false>(1.0f, Q);
        Q *= dppf<0x112, false>(1.0f, Q);
        Q *= dppf<0x114, false>(1.0f, Q);
        Q *= dppf<0x118, false>(1.0f, Q);
        const int   row  = lane >> 4;
        const float Q47  = __shfl(Q, 47, 64);  // full row-2 product (setup only)
        const float QmA  = (row == 1 || row == 3) ? Q : 0.0f;          // bcast15 coeff
        const float QmB  = (row == 2) ? Q : ((row == 3) ? Q * Q47 : 0.0f);  // bcast31

        auto dchain = [&](float fMn, float f0) -> float {
            float fMp = dppf<0x138, false>(f0, fMn);   // wave_shr1, lane0 <- f0
            float y = AjM2D * fMp;
            y = fmaf(V1,  dppf<0x111, true>(y, y), y);
            y = fmaf(V2,  dppf<0x112, true>(y, y), y);
            y = fmaf(V4,  dppf<0x114, true>(y, y), y);
            y = fmaf(V8,  dppf<0x118, true>(y, y), y);
            y = fmaf(QmA, dppf<0x142, true>(y, y), y);  // row_bcast15
            y = fmaf(QmB, dppf<0x143, true>(y, y), y);  // row_bcast31
            return y;
        };

        auto esel_of = [&](unsigned long long m0, unsigned long long m1,
                           int sh) -> float {
            int bit0 = (int)(m0 >> sh) & 1;
            int bit1 = (int)(m1 >> sh) & 1;
            float eA = bit0 ? E1 : E0;
            float eB = bit0 ? E3 : E2;
            return bit1 ? eB : eA;
        };

        // State (scaled linear space).
        float fM = 0.0f, fI = 0.0f;
        float fD = dchain(0.0f, 1.0f);   // init: fM0 = 1
        float LS = 0.0f;                 // accumulated log2 scale
        float fI0v;

        auto stepf = [&](float esel, float p0) {
            float pl = fmaf(A1M2M, fM, fmaf(A1I2M, fI, A1D2M * fD));
            float prev = dppf<0x138, false>(p0, pl);   // wave_shr1, lane0 <- p0
            float fMn = esel * prev;
            fI = fmaf(QA1M2I, fM, QA1I2I * fI);
            fD = dchain(fMn, 0.0f);
            fM = fMn;
        };

        auto rescale = [&]() {
            float m = fmaxf(fmaxf(fM, fI), fD);
            m = fmaxf(m, dppf<0xB1,  true>(m, m));   // quad_perm xor1
            m = fmaxf(m, dppf<0x4E,  true>(m, m));   // quad_perm xor2
            m = fmaxf(m, dppf<0x141, true>(m, m));   // row_half_mirror
            m = fmaxf(m, dppf<0x140, true>(m, m));   // row_mirror -> row max
            int mb = __builtin_bit_cast(int, m);
            unsigned u0 = (unsigned)__builtin_amdgcn_readlane(mb, 0);
            unsigned u1 = (unsigned)__builtin_amdgcn_readlane(mb, 16);
            unsigned u2 = (unsigned)__builtin_amdgcn_readlane(mb, 32);
            unsigned u3 = (unsigned)__builtin_amdgcn_readlane(mb, 48);
            unsigned ua = u0 > u1 ? u0 : u1;
            unsigned ub = u2 > u3 ? u2 : u3;
            unsigned um = ua > ub ? ua : ub;     // all values >= 0: uint cmp = float cmp
            int ee = (int)(um >> 23);            // exponent field
            float r = __builtin_bit_cast(float, (unsigned)(254 - ee) << 23);  // 2^(127-ee)
            LS += (float)(ee - 127);
            fM *= r; fI *= r; fD *= r; fI0v *= r;
        };

        // l = 0 peeled: only state-0 M path live (fM0 = 1).
        stepf(esel_of(b0lo, b1lo, 0), A0M2M);
        fI0v = QA0M2I;   // state-0 insert mass for step 1

        for (int l = 1; l < 64; ++l) {
            stepf(esel_of(b0lo, b1lo, l), A0I2M * fI0v);
            fI0v *= D0;
            if ((l & 7) == 7) rescale();
        }
        for (int l = 64; l < 128; ++l) {
            stepf(esel_of(b0hi, b1hi, l - 64), A0I2M * fI0v);
            fI0v *= D0;
            if ((l & 7) == 7) rescale();
        }

        // Final logsumexp at state K=64 (lane 63, row-64 coefficients).
        float F = fmaf(A1M2M, fM, fmaf(A1I2M, fI, A1D2M * fD));
        float loss = -(__builtin_amdgcn_logf(F) + LS) * kLn2;

        // KLD on lanes 0..15.
        float kt = 0.0f;
        if (lane < 16) {
            float mu = mug[(size_t)b * 16 + lane];
            float lv = lvg[(size_t)b * 16 + lane];
            kt = 1.0f + lv - mu * mu - fexp(lv);
        }
        kt += __shfl_xor(kt, 1, 64);
        kt += __shfl_xor(kt, 2, 64);
        kt += __shfl_xor(kt, 4, 64);
        kt += __shfl_xor(kt, 8, 64);
        float kldb = __shfl(-0.5f * kt, 0, 64);

        contrib = (loss + kldb) * (1.0f / 4096.0f);
    }

    if (lane == 63) part[wv] = (b < B) ? contrib : 0.0f;
    __syncthreads();
    if (tid == 0) {
        float bs = part[0] + part[1] + part[2] + part[3];
        // d_ws is poisoned to 0xAA bytes before every call. Use wsf[1] (float
        // accumulator, initial value = poisonf) and wsc[0] (uint counter,
        // initial value 0xAAAAAAAA). Device-scope atomics are cross-XCD safe.
        const float    poisonf = __builtin_bit_cast(float, 0xAAAAAAAAu);
        atomicAdd(&wsf[1], bs);
        __threadfence();
        unsigned old = atomicAdd(&wsc[0], 1u);
        if (old == 0xAAAAAAAAu + (unsigned)(gridDim.x - 1)) {
            __threadfence();
            float total = atomicAdd(&wsf[1], 0.0f);  // returns final sum
            out[0] = total - poisonf;
        }
    }
}

}  // namespace

extern "C" void kernel_launch(void* const* d_in, const int* in_sizes, int n_in,
                              void* d_out, int out_size, void* d_ws, size_t ws_size,
                              hipStream_t stream) {
    const int*   x  = (const int*)d_in[0];
    const float* a  = (const float*)d_in[1];
    const float* e  = (const float*)d_in[2];
    const float* mu = (const float*)d_in[3];
    const float* lv = (const float*)d_in[4];
    float* out = (float*)d_out;

    const int B = in_sizes[0] / 128;      // 4096
    const int grid = (B + 3) / 4;         // 4 waves (batch elements) per block

    phmm_vae_kernel<<<grid, 256, 0, stream>>>(x, a, e, mu, lv, out,
                                              (unsigned*)d_ws, (float*)d_ws, B);
}

// Round 5
// 95.622 us; speedup vs baseline: 2.1008x; 1.1510x over previous
//
#include <hip/hip_runtime.h>
#include <math.h>

// pHMM forward in LINEAR space (scaled) + KLD. One wave per batch element,
// lane j = state j+1; state 0 via closed form. Delete-chain = single-instr
// DPP scan: v_mul_f32_dpp (shift+coeff) + 6x v_fmac_f32_dpp (row_shr 1/2/4/8,
// row_bcast 15/31) with explicit s_nop hazard separation. A1D2M folded into
// the scan (z = A1D2M*fD) via coefficient change. Rescale every 8 steps by an
// exact power of 2. Finale: plain per-block store + tiny reduce kernel (no
// atomics -> no serialized tail).

namespace {

constexpr float kLog2e = 1.4426950408889634f;
constexpr float kLn2   = 0.6931471805599453f;

__device__ __forceinline__ float fexp(float x) {  // e^x
    return __builtin_amdgcn_exp2f(x * kLog2e);
}

template <int CTRL, bool BC>
__device__ __forceinline__ float dppf(float old, float src) {
    int r = __builtin_amdgcn_update_dpp(__builtin_bit_cast(int, old),
                                        __builtin_bit_cast(int, src),
                                        CTRL, 0xF, 0xF, BC);
    return __builtin_bit_cast(float, r);
}

__global__ __launch_bounds__(256) void phmm_vae_kernel(
    const int* __restrict__ xg,    // (B,128) int32
    const float* __restrict__ ag,  // (B,65,7)
    const float* __restrict__ eg,  // (B,64,4)
    const float* __restrict__ mug, // (B,16)
    const float* __restrict__ lvg, // (B,16)
    float* __restrict__ partials, int B)
{
    const int tid  = threadIdx.x;
    const int lane = tid & 63;
    const int wv   = tid >> 6;
    const int b    = (blockIdx.x << 2) + wv;

    __shared__ float part[4];
    float contrib = 0.0f;

    if (b < B) {
        const float* ab = ag + (size_t)b * (65 * 7);
        const float* eb = eg + (size_t)b * (64 * 4);
        const int*   xb = xg + (size_t)b * 128;

        const int j = lane;
        // Row j: d-chain coeffs for state j+1. Row j+1: own-state coeffs.
        const float a2  = ab[j * 7 + 2];             // ln AjM2D
        const float a6  = ab[j * 7 + 6];             // ln AjD2D
        const float a5  = ab[(j + 1) * 7 + 5];       // ln w = ln A1D2M
        const float A1M2M  = fexp(ab[(j + 1) * 7 + 0]);
        const float QA1M2I = 0.25f * fexp(ab[(j + 1) * 7 + 1]);
        const float A1I2M  = fexp(ab[(j + 1) * 7 + 3]);
        const float QA1I2I = 0.25f * fexp(ab[(j + 1) * 7 + 4]);
        // State-0 row (wave-uniform).
        const float A0M2M  = fexp(ab[0]);
        const float QA0M2I = 0.25f * fexp(ab[1]);
        const float A0I2M  = fexp(ab[3]);
        const float D0     = 0.25f * fexp(ab[4]);

        float4 ev = *reinterpret_cast<const float4*>(eb + j * 4);
        const float E0 = fexp(ev.x), E1 = fexp(ev.y);
        const float E2 = fexp(ev.z), E3 = fexp(ev.w);

        const int xlo = xb[lane];
        const int xhi = xb[64 + lane];
        const unsigned long long b0lo = __ballot(xlo & 1);
        const unsigned long long b1lo = __ballot(xlo & 2);
        const unsigned long long b0hi = __ballot(xhi & 1);
        const unsigned long long b1hi = __ballot(xhi & 2);

        // Folded scan coefficients: z = w*fD with w = A1D2M.
        // dh[j] = d[j] * w[j]/w[j-1];  chat[j] = w[j]*AjM2D[j]*fMn[j-1].
        const float a5p = dppf<0x138, false>(0.0f, a5);   // ln w[j-1] (lane0: 0)
        const float dh  = fexp(a6 + a5 - a5p);
        const float wM2D = fexp(a2 + a5);                 // w[j]*AjM2D[j]
        // Emission of state j (= lane j-1's E), folded into C.
        const float C0 = wM2D * dppf<0x138, false>(0.0f, E0);
        const float C1 = wM2D * dppf<0x138, false>(0.0f, E1);
        const float C2 = wM2D * dppf<0x138, false>(0.0f, E2);
        const float C3 = wM2D * dppf<0x138, false>(0.0f, E3);

        // Row-local segment products of dh at distances 1/2/4/8, premasked.
        const float V1 = dh;
        const float V2 = V1 * dppf<0x111, false>(1.0f, V1);
        const float V4 = V2 * dppf<0x112, false>(1.0f, V2);
        const float V8 = V4 * dppf<0x114, false>(1.0f, V4);
        const float V1m = (lane >= 1)  ? V1 : 0.0f;
        const float V2m = (lane >= 2)  ? V2 : 0.0f;
        const float V4m = (lane >= 4)  ? V4 : 0.0f;
        const float V8m = (lane >= 8)  ? V8 : 0.0f;
        // Row-local inclusive prefix product Q[j].
        float Q = dh;
        Q *= dppf<0x111, false>(1.0f, Q);
        Q *= dppf<0x112, false>(1.0f, Q);
        Q *= dppf<0x114, false>(1.0f, Q);
        Q *= dppf<0x118, false>(1.0f, Q);
        const int   row = lane >> 4;
        const float Q47 = __shfl(Q, 47, 64);
        const float QmA = (row == 1 || row == 3) ? Q : 0.0f;               // bcast15
        const float QmB = (row == 2) ? Q : ((row == 3) ? Q * Q47 : 0.0f);  // bcast31

        // Single-instruction DPP scan: y = Cs*shr1(prev), then 6 fmac levels.
        // s_nop 1 covers the VALU-write -> DPP-read hazard (2 wait states).
        auto scan_asm = [&](float prev, float Cs) -> float {
            float y;
            asm("s_nop 1\n\t"
                "v_mul_f32_dpp %0, %1, %2 wave_shr:1 row_mask:0xf bank_mask:0xf bound_ctrl:0\n\t"
                "s_nop 1\n\t"
                "v_fmac_f32_dpp %0, %0, %3 row_shr:1 row_mask:0xf bank_mask:0xf bound_ctrl:0\n\t"
                "s_nop 1\n\t"
                "v_fmac_f32_dpp %0, %0, %4 row_shr:2 row_mask:0xf bank_mask:0xf bound_ctrl:0\n\t"
                "s_nop 1\n\t"
                "v_fmac_f32_dpp %0, %0, %5 row_shr:4 row_mask:0xf bank_mask:0xf bound_ctrl:0\n\t"
                "s_nop 1\n\t"
                "v_fmac_f32_dpp %0, %0, %6 row_shr:8 row_mask:0xf bank_mask:0xf bound_ctrl:0\n\t"
                "s_nop 1\n\t"
                "v_fmac_f32_dpp %0, %0, %7 row_bcast:15 row_mask:0xf bank_mask:0xf bound_ctrl:0\n\t"
                "s_nop 1\n\t"
                "v_fmac_f32_dpp %0, %0, %8 row_bcast:31 row_mask:0xf bank_mask:0xf bound_ctrl:0"
                : "=&v"(y)
                : "v"(prev), "v"(Cs), "v"(V1m), "v"(V2m), "v"(V4m), "v"(V8m),
                  "v"(QmA), "v"(QmB));
            return y;
        };

        // Initial z0 = w*fD_init (fM_init = [1,0,..]): intrinsic scan (setup).
        float y0 = (lane == 0) ? wM2D : 0.0f;
        y0 = fmaf(V1m, dppf<0x111, true>(0.0f, y0), y0);
        y0 = fmaf(V2m, dppf<0x112, true>(0.0f, y0), y0);
        y0 = fmaf(V4m, dppf<0x114, true>(0.0f, y0), y0);
        y0 = fmaf(V8m, dppf<0x118, true>(0.0f, y0), y0);
        y0 = fmaf(QmA, dppf<0x142, true>(0.0f, y0), y0);
        y0 = fmaf(QmB, dppf<0x143, true>(0.0f, y0), y0);

        float fM = 0.0f, fI = 0.0f;
        float pl = y0;          // pl entering step 0 (fM=fI=0 -> pl = z0)
        float fI0v = 0.0f;
        float LS = 0.0f;        // accumulated log2 scale

#pragma unroll 8
        for (int l = 0; l < 128; ++l) {
            const unsigned long long m0 = (l < 64) ? b0lo : b0hi;
            const unsigned long long m1 = (l < 64) ? b1lo : b1hi;
            const int sh = l & 63;
            const int bit0 = (int)(m0 >> sh) & 1;
            const int bit1 = (int)(m1 >> sh) & 1;
            const float Es = bit1 ? (bit0 ? E3 : E2) : (bit0 ? E1 : E0);
            const float Cs = bit1 ? (bit0 ? C3 : C2) : (bit0 ? C1 : C0);

            const float p0v = (l == 0) ? A0M2M : A0I2M * fI0v;
            const float prev = dppf<0x138, false>(p0v, pl);  // lane0 <- p0v
            const float fMn = Es * prev;
            const float z = scan_asm(prev, Cs);
            fI = fmaf(QA1M2I, fM, QA1I2I * fI);
            fM = fMn;
            pl = fmaf(A1M2M, fM, fmaf(A1I2M, fI, z));
            fI0v = (l == 0) ? QA0M2I : fI0v * D0;

            if ((l & 7) == 7) {
                float m = fmaxf(fmaxf(fM, fI), pl);
                m = fmaxf(m, dppf<0xB1,  true>(0.0f, m));   // quad xor1
                m = fmaxf(m, dppf<0x4E,  true>(0.0f, m));   // quad xor2
                m = fmaxf(m, dppf<0x141, true>(0.0f, m));   // half mirror
                m = fmaxf(m, dppf<0x140, true>(0.0f, m));   // mirror -> row max
                m = fmaxf(m, 1e-35f);
                int mb = __builtin_bit_cast(int, m);
                unsigned u0 = (unsigned)__builtin_amdgcn_readlane(mb, 0);
                unsigned u1 = (unsigned)__builtin_amdgcn_readlane(mb, 16);
                unsigned u2 = (unsigned)__builtin_amdgcn_readlane(mb, 32);
                unsigned u3 = (unsigned)__builtin_amdgcn_readlane(mb, 48);
                unsigned ua = u0 > u1 ? u0 : u1;
                unsigned ub = u2 > u3 ? u2 : u3;
                unsigned um = ua > ub ? ua : ub;   // >=0: uint cmp = float cmp
                int ee = (int)(um >> 23);
                float r = __builtin_bit_cast(float, (unsigned)(254 - ee) << 23);
                LS += (float)(ee - 127);
                fM *= r; fI *= r; pl *= r; fI0v *= r;
            }
        }

        // F = forward prob into end state = pl after step 127, lane 63.
        const float Fv = __shfl(pl, 63, 64);
        const float loss = -(__builtin_amdgcn_logf(Fv) + LS) * kLn2;

        // KLD on lanes 0..15.
        float kt = 0.0f;
        if (lane < 16) {
            float mu = mug[(size_t)b * 16 + lane];
            float lv = lvg[(size_t)b * 16 + lane];
            kt = 1.0f + lv - mu * mu - fexp(lv);
        }
        kt += __shfl_xor(kt, 1, 64);
        kt += __shfl_xor(kt, 2, 64);
        kt += __shfl_xor(kt, 4, 64);
        kt += __shfl_xor(kt, 8, 64);
        float kldb = __shfl(-0.5f * kt, 0, 64);

        contrib = (loss + kldb) * (1.0f / 4096.0f);
    }

    if (lane == 63) part[wv] = (b < B) ? contrib : 0.0f;
    __syncthreads();
    if (tid == 0) {
        partials[blockIdx.x] = part[0] + part[1] + part[2] + part[3];
    }
}

__global__ __launch_bounds__(256) void reduce_kernel(
    const float* __restrict__ p, float* __restrict__ out, int n)
{
    const int tid = threadIdx.x;
    float s = 0.0f;
    for (int i = tid; i < n; i += 256) s += p[i];
    s += __shfl_xor(s, 1, 64);
    s += __shfl_xor(s, 2, 64);
    s += __shfl_xor(s, 4, 64);
    s += __shfl_xor(s, 8, 64);
    s += __shfl_xor(s, 16, 64);
    s += __shfl_xor(s, 32, 64);
    __shared__ float ps[4];
    if ((tid & 63) == 0) ps[tid >> 6] = s;
    __syncthreads();
    if (tid == 0) out[0] = ps[0] + ps[1] + ps[2] + ps[3];
}

}  // namespace

extern "C" void kernel_launch(void* const* d_in, const int* in_sizes, int n_in,
                              void* d_out, int out_size, void* d_ws, size_t ws_size,
                              hipStream_t stream) {
    const int*   x  = (const int*)d_in[0];
    const float* a  = (const float*)d_in[1];
    const float* e  = (const float*)d_in[2];
    const float* mu = (const float*)d_in[3];
    const float* lv = (const float*)d_in[4];
    float* out = (float*)d_out;
    float* partials = (float*)d_ws;

    const int B = in_sizes[0] / 128;      // 4096
    const int grid = (B + 3) / 4;         // 4 waves (batch elements) per block

    phmm_vae_kernel<<<grid, 256, 0, stream>>>(x, a, e, mu, lv, partials, B);
    reduce_kernel<<<1, 256, 0, stream>>>(partials, out, grid);
}